// Round 21
// baseline (294.903 us; speedup 1.0000x reference)
//
#include <hip/hip_runtime.h>
#include <math.h>

// feat_arm/feat_up: [16,144,64,64] f32
// off_w: [144,288,3,3], off_b: [144]
// dcn_w: [256,144,3,3], dcn_b: [256]
// out: [16,256,64,64] f32 (silu)
constexpr int BN = 16;
constexpr int C_IN = 144, C_CAT = 288, C_OFF = 144, C_OUT = 256;
constexpr int OFFG = 8, CG = 18;

constexpr int FUB_ELEMS  = C_IN * BN * 4096;      // 9,437,184 f16 planar feat_up
constexpr int OFFP_ELEMS = BN * 72 * 4096;        // 4,718,592 u32 fp16 offset pairs
constexpr int WOFF_PACK = 9 * 9 * 9 * 512;        // bf16 (cb,tap,mtile,lane,i)
constexpr int WDCN_PACK = 8 * 6 * 16 * 512;       // f16  (t=g*6+ks, mtile, lane, i)

typedef __attribute__((ext_vector_type(8))) short bf16x8;
typedef __attribute__((ext_vector_type(8))) _Float16 f16x8;
typedef __attribute__((ext_vector_type(2))) _Float16 f16x2;
typedef __attribute__((ext_vector_type(4))) float f32x4;
typedef __attribute__((ext_vector_type(4))) unsigned u32x4;

__device__ __forceinline__ unsigned short f2bf(float f) {
  unsigned u = __builtin_bit_cast(unsigned, f);
  return (unsigned short)((u + 0x7FFFu + ((u >> 16) & 1u)) >> 16);  // RNE, finite inputs
}

__device__ __forceinline__ unsigned packh2(float a, float b) {
  unsigned short ha = __builtin_bit_cast(unsigned short, (_Float16)a);
  unsigned short hb = __builtin_bit_cast(unsigned short, (_Float16)b);
  return (unsigned)ha | ((unsigned)hb << 16);
}
__device__ __forceinline__ float h2f_lo(unsigned u) {
  return (float)__builtin_bit_cast(_Float16, (unsigned short)(u & 0xFFFFu));
}
__device__ __forceinline__ float h2f_hi(unsigned u) {
  return (float)__builtin_bit_cast(_Float16, (unsigned short)(u >> 16));
}

// ---------------------------------------------------------------------------
// Kernel 1: prep — weight packs only (fuB produced by offs_conv).
// ---------------------------------------------------------------------------
__global__ __launch_bounds__(256) void prep(
    const float* __restrict__ off_w, const float* __restrict__ dcn_w,
    unsigned short* __restrict__ wo, _Float16* __restrict__ wd) {
  int idx = blockIdx.x * 256 + threadIdx.x;
  if (idx < WOFF_PACK) {
    int i = idx & 7, lane = (idx >> 3) & 63, t = idx >> 9;
    int mt = t % 9; t /= 9;
    int tap = t % 9, cb = t / 9;
    int co = mt * 16 + (lane & 15);
    int ci = cb * 32 + ((lane >> 4) << 3) + i;
    wo[idx] = f2bf(off_w[(co * C_CAT + ci) * 9 + tap]);
  }
  if (idx < WDCN_PACK) {
    int i = idx & 7, lane = (idx >> 3) & 63, t = idx >> 9;
    int mt = t & 15; t >>= 4;
    int ks = t % 6, g = t / 6;
    int co = mt * 16 + (lane & 15);
    int r = ks * 32 + ((lane >> 4) << 3) + i;
    float v = 0.f;
    if (r < 162) {
      int ci = r / 9, tap = r - ci * 9;
      v = dcn_w[(co * C_IN + g * CG + ci) * 9 + tap];
    }
    wd[idx] = (_Float16)v;
  }
}

// ---------------------------------------------------------------------------
// Kernel 2: offset conv via MFMA (r20-proven: XCD swizzle + setprio + fuB
// emission in the staging loop).
// ---------------------------------------------------------------------------
__global__ __launch_bounds__(256) void offs_conv_mfma(
    const float* __restrict__ fa, const float* __restrict__ fu,
    const unsigned short* __restrict__ wt, const float* __restrict__ bias,
    unsigned* __restrict__ offp, _Float16* __restrict__ fuB) {
  const int bid = (blockIdx.x & 7) * 64 + (blockIdx.x >> 3);  // XCD swizzle
  const int b = bid >> 5;
  const int y0 = (bid & 31) << 1;
  const int tid = threadIdx.x;
  const int wave = tid >> 6, lane = tid & 63;
  const int kg = lane >> 4, ln = lane & 15;

  __shared__ __align__(16) unsigned short xs[4 * 66 * 32];

  f32x4 acc[9][2];
#pragma unroll
  for (int m = 0; m < 9; ++m)
#pragma unroll
    for (int n = 0; n < 2; ++n) acc[m][n] = {0.f, 0.f, 0.f, 0.f};

  for (int cb = 0; cb < 9; ++cb) {
    __syncthreads();
    for (int idx = tid; idx < 2112; idx += 256) {
      int q = idx / 264;
      int rem = idx - q * 264;
      int row = rem / 66;
      int cc = rem - row * 66;
      int y = y0 - 1 + row, x = cc - 1;
      ushort4 wv = make_ushort4(0, 0, 0, 0);
      if (y >= 0 && y < 64 && x >= 0 && x < 64) {
        int cib = cb * 32 + (q << 2);
        const float* p = (cib < C_IN)
                             ? fa + (((size_t)(b * C_IN + cib)) << 12)
                             : fu + (((size_t)(b * C_IN + cib - C_IN)) << 12);
        int o = (y << 6) + x;
        float v0 = p[o], v1 = p[o + 4096], v2 = p[o + 8192], v3 = p[o + 12288];
        wv.x = f2bf(v0);
        wv.y = f2bf(v1);
        wv.z = f2bf(v2);
        wv.w = f2bf(v3);
        // emit fuB for interior rows (y ∈ {y0, y0+1}) of fu channels
        if (cib >= C_IN && row >= 1 && row <= 2) {
          _Float16* fb = fuB + (((size_t)(b * C_IN + cib - C_IN)) << 12) + o;
          fb[0] = (_Float16)v0;
          fb[4096] = (_Float16)v1;
          fb[8192] = (_Float16)v2;
          fb[12288] = (_Float16)v3;
        }
      }
      int e = ((row * 66 + cc) << 5) + (((q >> 1) ^ (cc & 3)) << 3) + ((q & 1) << 2);
      *(ushort4*)&xs[e] = wv;
    }
    __syncthreads();

    for (int tap = 0; tap < 9; ++tap) {
      const int ky = tap / 3, kx = tap - ky * 3;
      bf16x8 a[9];
      const unsigned short* wp = wt + (((size_t)(cb * 9 + tap) * 9) << 9) + (lane << 3);
#pragma unroll
      for (int m = 0; m < 9; ++m) a[m] = *(const bf16x8*)(wp + (m << 9));
#pragma unroll
      for (int n = 0; n < 2; ++n) {
        int px = ((wave << 1) + n) * 16 + ln;
        int row = (px >> 6) + ky, cc = (px & 63) + kx;
        int e = ((row * 66 + cc) << 5) + ((kg ^ (cc & 3)) << 3);
        bf16x8 bv = *(const bf16x8*)&xs[e];
        __builtin_amdgcn_s_setprio(1);
#pragma unroll
        for (int m = 0; m < 9; ++m)
          acc[m][n] = __builtin_amdgcn_mfma_f32_16x16x32_bf16(a[m], bv, acc[m][n], 0, 0, 0);
        __builtin_amdgcn_s_setprio(0);
      }
    }
  }

  // epilogue: C/D col=lane&15 (px), row=(lane>>4)*4+r (co); pack pairs fp16
#pragma unroll
  for (int n = 0; n < 2; ++n) {
    int px = ((wave << 1) + n) * 16 + ln;
    int y = y0 + (px >> 6), x = px & 63;
#pragma unroll
    for (int m = 0; m < 9; ++m) {
      int cob = m * 16 + (kg << 2);
#pragma unroll
      for (int rr = 0; rr < 4; rr += 2) {
        unsigned v = packh2(acc[m][n][rr] + bias[cob + rr],
                            acc[m][n][rr + 1] + bias[cob + rr + 1]);
        offp[(((size_t)(b * 72 + ((cob + rr) >> 1))) << 12) + (y << 6) + x] = v;
      }
    }
  }
}

// ---------------------------------------------------------------------------
// Kernel 3: deformable conv via MFMA. r20 skeleton with phase 3 BARRIER-FREE:
// A-fragments load global->register via asm volatile global_load_dwordx4
// (8 pinned loads issued back-to-back — defeats the compiler serialization
// that killed r5/r13/r16), then s_waitcnt vmcnt(0) + sched_barrier(0)
// (rule #18) before the MFMA cluster. Each wave waits only its OWN loads;
// no cross-wave A dependency -> no per-K-step barrier. 2 barriers/group
// (was 8). wl/tri-buffer deleted: LDS 75.3 -> 25.9 KB. wd is L2-resident
// (FETCH=24MB), so the ~250cyc load latency is covered by 16 free-running
// waves/CU. Revert trigger: WRITE_SIZE > 70MB (spill).
// ---------------------------------------------------------------------------
__global__ __launch_bounds__(512, 4) void dcn_mfma(
    const _Float16* __restrict__ fuB, const unsigned* __restrict__ offp,
    const _Float16* __restrict__ wt, const float* __restrict__ bias,
    float* __restrict__ out) {
  const int bid = (blockIdx.x & 7) * 128 + (blockIdx.x >> 3);  // XCD swizzle
  const int b = bid >> 6, h = bid & 63;
  const int tid = threadIdx.x;
  const int wave = tid >> 6, lane = tid & 63;
  const int kg = lane >> 4, ln = lane & 15;
  const int wm = wave >> 2, wn = wave & 3;   // M-half, N-tile
  const int px = (wn << 4) + ln;             // this wave's pixel (n index)

  __shared__ __align__(16) unsigned short colsT[64 * 202];// [px][r pad 202], f16

  f32x4 acc[8];
#pragma unroll
  for (int m = 0; m < 8; ++m) acc[m] = {0.f, 0.f, 0.f, 0.f};

  // zero K-pad region r in [162,192) once (15 u32 per px) — MFMA-safe pad
  for (int i = tid; i < 64 * 15; i += 512) {
    int p = i / 15, d = i - p * 15;
    *(unsigned*)&colsT[p * 202 + 162 + 2 * d] = 0u;
  }

  // geometry for (group, tap, pixel p), x-corner-pair folded (r11-proven):
  //   gg.x = iL0 | iL1<<16 ; gg.z = (wl0,wh0) f16 pair ; gg.w = (wl1,wh1)
  auto make_geo = [&](int gg_, int tap, int p) -> uint4 {
    int ky = tap / 3, kx = tap - ky * 3;
    unsigned op = offp[(((size_t)(b * 72 + gg_ * 9 + tap)) << 12) + (h << 6) + p];
    float oy = h2f_lo(op), ox = h2f_hi(op);
    float py = (float)(h - 1 + ky) + oy;
    float pxs = (float)(p - 1 + kx) + ox;
    float y0f = floorf(py), x0f = floorf(pxs);
    int y0 = (int)y0f, x0 = (int)x0f;
    float fy = py - y0f, fx = pxs - x0f;
    float vy0 = (y0 >= 0 && y0 < 64) ? 1.f : 0.f;
    float vy1 = (y0 + 1 >= 0 && y0 + 1 < 64) ? 1.f : 0.f;
    float vx0 = (x0 >= 0 && x0 < 64) ? 1.f : 0.f;
    float vx1 = (x0 + 1 >= 0 && x0 + 1 < 64) ? 1.f : 0.f;
    float a0 = (1.f - fx) * vx0;
    float a1 = fx * vx1;
    float wlo = (x0 == -1) ? a1 : (x0 == 63 ? 0.f : a0);
    float whi = (x0 == 63) ? a0 : (x0 == -1 ? 0.f : a1);
    int xL = min(max(x0, 0), 62);
    int yc0 = min(max(y0, 0), 63), yc1 = min(max(y0 + 1, 0), 63);
    float cy0 = (1.f - fy) * vy0, cy1 = fy * vy1;
    uint4 r;
    r.x = (unsigned)((yc0 << 6) + xL) | ((unsigned)((yc1 << 6) + xL) << 16);
    r.y = 0u;
    r.z = packh2(cy0 * wlo, cy0 * whi);
    r.w = packh2(cy1 * wlo, cy1 * whi);
    return r;
  };

  for (int g = 0; g < OFFG; ++g) {
    __syncthreads();  // prev group's colsT readers done

    // ---- phase 1: wave w computes tap-w AND tap-8 geometry in registers
    uint4 gg = make_geo(g, wave, lane);
    uint4 g8 = make_geo(g, 8, lane);

    // ---- phase 2: gather, FULL-ISSUE; packed fp16 sample math (r20-proven)
    const _Float16* gbase = fuB + (((size_t)(b * C_IN + g * CG)) << 12);
    {
      const int iL0 = gg.x & 0xFFFFu, iL1 = gg.x >> 16;
      const f16x2 w0 = __builtin_bit_cast(f16x2, gg.z);
      const f16x2 w1 = __builtin_bit_cast(f16x2, gg.w);
      const int j0 = g8.x & 0xFFFFu, j1 = g8.x >> 16;
      const f16x2 u0 = __builtin_bit_cast(f16x2, g8.z);
      const f16x2 u1 = __builtin_bit_cast(f16x2, g8.w);
      const int n8 = (wave < 2) ? 3 : 2;

      unsigned d0[18], d1[18], e0[3], e1[3];
#pragma unroll
      for (int u = 0; u < 18; ++u) {          // 36 independent 4B loads
        const _Float16* pl = gbase + ((size_t)u << 12);
        __builtin_memcpy(&d0[u], pl + iL0, 4);   // f16 pair (xL, xL+1)
        __builtin_memcpy(&d1[u], pl + iL1, 4);
      }
#pragma unroll
      for (int u = 0; u < 3; ++u) {           // up to 6 tap-8 loads
        if (u < n8) {
          const _Float16* pl = gbase + ((size_t)(wave + 8 * u) << 12);
          __builtin_memcpy(&e0[u], pl + j0, 4);
          __builtin_memcpy(&e1[u], pl + j1, 4);
        }
      }
#pragma unroll
      for (int u = 0; u < 18; ++u) {
        f16x2 sp = __builtin_bit_cast(f16x2, d0[u]) * w0 +
                   __builtin_bit_cast(f16x2, d1[u]) * w1;   // pk_mul + pk_fma
        _Float16 s = sp[0] + sp[1];
        colsT[lane * 202 + u * 9 + wave] = __builtin_bit_cast(unsigned short, s);
      }
#pragma unroll
      for (int u = 0; u < 3; ++u) {
        if (u < n8) {
          f16x2 sp = __builtin_bit_cast(f16x2, e0[u]) * u0 +
                     __builtin_bit_cast(f16x2, e1[u]) * u1;
          _Float16 s = sp[0] + sp[1];
          colsT[lane * 202 + (wave + 8 * u) * 9 + 8] =
              __builtin_bit_cast(unsigned short, s);
        }
      }
    }
    __syncthreads();  // colsT ready (drains gather loads too)

    // ---- phase 3: 6 MFMA K-steps, BARRIER-FREE; A via forced-batch asm
    for (int ks = 0; ks < 6; ++ks) {
      // A: 8 pinned global_load_dwordx4, issued back-to-back (L2-hot)
      const _Float16* wpA =
          wt + (size_t)(g * 6 + ks) * 8192 + (wm * 8) * 512 + (size_t)lane * 8;
      const _Float16* wpB = wpA + 2048;  // rows 4..7 (4096 B ahead)
      u32x4 r0, r1, r2, r3, r4, r5, r6, r7;
      asm volatile("global_load_dwordx4 %0, %1, off offset:0"
                   : "=v"(r0) : "v"(wpA));
      asm volatile("global_load_dwordx4 %0, %1, off offset:1024"
                   : "=v"(r1) : "v"(wpA));
      asm volatile("global_load_dwordx4 %0, %1, off offset:2048"
                   : "=v"(r2) : "v"(wpA));
      asm volatile("global_load_dwordx4 %0, %1, off offset:3072"
                   : "=v"(r3) : "v"(wpA));
      asm volatile("global_load_dwordx4 %0, %1, off offset:0"
                   : "=v"(r4) : "v"(wpB));
      asm volatile("global_load_dwordx4 %0, %1, off offset:1024"
                   : "=v"(r5) : "v"(wpB));
      asm volatile("global_load_dwordx4 %0, %1, off offset:2048"
                   : "=v"(r6) : "v"(wpB));
      asm volatile("global_load_dwordx4 %0, %1, off offset:3072"
                   : "=v"(r7) : "v"(wpB));

      // B fragment: 4 x ds_read_b32 (odd-dword row stride, conflict-free);
      // LDS latency overlaps the in-flight A loads.
      int cbase = px * 202 + ks * 32 + (kg << 3);
      u32x4 bu;
      bu[0] = *(const unsigned*)&colsT[cbase];
      bu[1] = *(const unsigned*)&colsT[cbase + 2];
      bu[2] = *(const unsigned*)&colsT[cbase + 4];
      bu[3] = *(const unsigned*)&colsT[cbase + 6];
      f16x8 bv = __builtin_bit_cast(f16x8, bu);

      // wait own A loads only (no cross-wave dependency), pin order (#18)
      asm volatile("s_waitcnt vmcnt(0)" ::: "memory");
      __builtin_amdgcn_sched_barrier(0);

      __builtin_amdgcn_s_setprio(1);
      acc[0] = __builtin_amdgcn_mfma_f32_16x16x32_f16(
          __builtin_bit_cast(f16x8, r0), bv, acc[0], 0, 0, 0);
      acc[1] = __builtin_amdgcn_mfma_f32_16x16x32_f16(
          __builtin_bit_cast(f16x8, r1), bv, acc[1], 0, 0, 0);
      acc[2] = __builtin_amdgcn_mfma_f32_16x16x32_f16(
          __builtin_bit_cast(f16x8, r2), bv, acc[2], 0, 0, 0);
      acc[3] = __builtin_amdgcn_mfma_f32_16x16x32_f16(
          __builtin_bit_cast(f16x8, r3), bv, acc[3], 0, 0, 0);
      acc[4] = __builtin_amdgcn_mfma_f32_16x16x32_f16(
          __builtin_bit_cast(f16x8, r4), bv, acc[4], 0, 0, 0);
      acc[5] = __builtin_amdgcn_mfma_f32_16x16x32_f16(
          __builtin_bit_cast(f16x8, r5), bv, acc[5], 0, 0, 0);
      acc[6] = __builtin_amdgcn_mfma_f32_16x16x32_f16(
          __builtin_bit_cast(f16x8, r6), bv, acc[6], 0, 0, 0);
      acc[7] = __builtin_amdgcn_mfma_f32_16x16x32_f16(
          __builtin_bit_cast(f16x8, r7), bv, acc[7], 0, 0, 0);
      __builtin_amdgcn_s_setprio(0);
    }
  }

  // ---- epilogue: bias + SiLU.  C/D: col(px)=lane&15, row=kg*4+r
#pragma unroll
  for (int j = 0; j < 8; ++j) {
    int cob = (wm * 8 + j) * 16 + (kg << 2);
#pragma unroll
    for (int r = 0; r < 4; ++r) {
      float y = acc[j][r] + bias[cob + r];
      out[(((size_t)(b * C_OUT + cob + r)) << 12) + (h << 6) + px] =
          y / (1.f + expf(-y));
    }
  }
}

// ---------------------------------------------------------------------------
extern "C" void kernel_launch(void* const* d_in, const int* in_sizes, int n_in,
                              void* d_out, int out_size, void* d_ws, size_t ws_size,
                              hipStream_t stream) {
  const float* feat_arm = (const float*)d_in[0];
  const float* feat_up  = (const float*)d_in[1];
  const float* off_w    = (const float*)d_in[2];
  const float* off_b    = (const float*)d_in[3];
  const float* dcn_w    = (const float*)d_in[4];
  const float* dcn_b    = (const float*)d_in[5];
  float* out = (float*)d_out;

  // ws layout (identical sizes to rounds 12-20):
  _Float16* fuB = (_Float16*)d_ws;                        // FUB_ELEMS f16
  unsigned* offp = (unsigned*)(fuB + FUB_ELEMS);          // OFFP_ELEMS u32
  unsigned short* wo = (unsigned short*)(offp + OFFP_ELEMS);
  _Float16* wd = (_Float16*)(wo + WOFF_PACK);

  prep<<<(WDCN_PACK + 255) / 256, 256, 0, stream>>>(off_w, dcn_w, wo, wd);
  offs_conv_mfma<<<BN * 32, 256, 0, stream>>>(feat_arm, feat_up, wo, off_b, offp, fuB);
  dcn_mfma<<<BN * 64, 512, 0, stream>>>(fuB, offp, wd, dcn_b, out);
}